// Round 9
// baseline (1243.216 us; speedup 1.0000x reference)
//
#include <hip/hip_runtime.h>
#include <math.h>

#define N_V   8192
#define N_E   4096
#define V_HID 128
#define H0_   64
#define CAP   96      // row nz capacity  (mean 41, sigma 6.4)
#define CAPC  144     // col nz capacity  (mean 82, sigma 9.0)
#define BN_EPS 1e-5f
#define GRID  1024u   // 4 blocks/CU x 256 CU: exactly co-resident (see launch_bounds)

typedef unsigned int u32;
typedef unsigned long long u64;

__device__ __forceinline__ void grid_sync(u32* bar) {
    __threadfence();                        // release my writes to device scope
    __syncthreads();
    if (threadIdx.x == 0) {
        u32 ticket = atomicAdd(bar, 1u) + 1u;
        u32 target = ((ticket + GRID - 1u) / GRID) * GRID;   // end of this generation
        while (atomicAdd(bar, 0u) < target) __builtin_amdgcn_s_sleep(32);
    }
    __syncthreads();
    __threadfence();                        // acquire: no stale reads after barrier
}

__global__ __launch_bounds__(256, 4) void k_fused(
    const float* __restrict__ X, const float* __restrict__ th1,
    const float* __restrict__ Dv, const float* __restrict__ De,
    const float* __restrict__ Hf, const float* __restrict__ W,
    const float* __restrict__ th2, const float* __restrict__ gm,
    const float* __restrict__ bt,
    float* __restrict__ P,                  // aliased as X1 after stage 2
    float* __restrict__ Mp,
    u32* __restrict__ nzlist, u32* __restrict__ nzcnt,
    u32* __restrict__ colcnt, u32* __restrict__ colentry,
    float* __restrict__ bnp, float* __restrict__ P2, float* __restrict__ M2p,
    u32* bar, float* __restrict__ out)
{
    __shared__ __align__(16) char shmem[36 * 1024];
    int tid = threadIdx.x;
    int lane = tid & 63, wv = tid >> 6;
    int blk = blockIdx.x;

    // ================= stage 0: P[n,h] = Dv[n] * (X @ th1)[n,h]  (8 rows/block)
    {
        float (*Th)[H0_]   = (float(*)[H0_])shmem;                // 128x64 = 32 KB
        float (*Xs)[V_HID] = (float(*)[V_HID])(shmem + 32768);    // 8x128  = 4 KB
        int n0 = blk * 8;
        for (int i = tid; i < 2048; i += 256) {                   // th1: 2048 float4
            float4 f = ((const float4*)th1)[i];
            int b = 4 * i;
            Th[b >> 6][(b & 63) + 0] = f.x;
            Th[b >> 6][(b & 63) + 1] = f.y;
            Th[b >> 6][(b & 63) + 2] = f.z;
            Th[b >> 6][(b & 63) + 3] = f.w;
        }
        {
            float4 f = ((const float4*)(X + (size_t)n0 * V_HID))[tid]; // 256 float4 = 8 rows
            int b = 4 * tid;
            Xs[b >> 7][(b & 127) + 0] = f.x;
            Xs[b >> 7][(b & 127) + 1] = f.y;
            Xs[b >> 7][(b & 127) + 2] = f.z;
            Xs[b >> 7][(b & 127) + 3] = f.w;
        }
        __syncthreads();
        int r0 = wv * 2;
        float a0 = 0.f, a1 = 0.f;
        for (int k = 0; k < V_HID; ++k) {
            float t = Th[k][lane];
            a0 += t * Xs[r0 + 0][k];
            a1 += t * Xs[r0 + 1][k];
        }
        P[(size_t)(n0 + r0 + 0) * H0_ + lane] = Dv[n0 + r0 + 0] * a0;
        P[(size_t)(n0 + r0 + 1) * H0_ + lane] = Dv[n0 + r0 + 1] * a1;
        __syncthreads();   // Th/Xs dead before stage 1 clobbers shmem
    }

    // ================= stage 1: scan H rows (8/block, 2/wave), build lists
    {
        u32 (*rowbuf)[CAP] = (u32(*)[CAP])shmem;                  // 4x96x4 = 1.5 KB
        u64 ltmask = (lane == 63) ? 0x7FFFFFFFFFFFFFFFull : ((1ull << lane) - 1ull);
#pragma unroll 1
        for (int rr = 0; rr < 2; ++rr) {
            int n = blk * 8 + wv * 2 + rr;
            const uint4* hrow4 = (const uint4*)(Hf + (size_t)n * N_E);
            uint4 q[16];
#pragma unroll
            for (int m = 0; m < 16; ++m)         // whole 16 KB row in flight
                q[m] = hrow4[m * 64 + lane];
            u32 cnt = 0;
#pragma unroll
            for (int m = 0; m < 16; ++m) {
                int ebase = (m * 64 + lane) * 4;
                u32 w4[4] = { q[m].x, q[m].y, q[m].z, q[m].w };
#pragma unroll
                for (int j = 0; j < 4; ++j) {
                    bool has = (w4[j] & 0x7FFFFFFFu) != 0u;
                    u64 bal = __ballot(has);
                    if (bal) {
                        if (has) {
                            u32 slot = cnt + (u32)__popcll(bal & ltmask);
                            if (slot < CAP) rowbuf[wv][slot] = (u32)(ebase + j);
                        }
                        cnt += (u32)__popcll(bal);
                    }
                }
            }
            if (cnt > CAP) cnt = CAP;
            if (lane == 0) nzcnt[n] = cnt;
            for (u32 i = lane; i < cnt; i += 64) {
                u32 e = rowbuf[wv][i];
                nzlist[(size_t)n * CAP + i] = e;
                u32 cs = atomicAdd(&colcnt[e], 1u);
                if (cs < CAPC) colentry[(size_t)e * CAPC + cs] = (u32)n;
            }
        }
    }
    grid_sync(bar);   // A: P + lists ready

    // ================= stage 2: Mp[e,:] = W*De * sum_colnz P[n,:]  (1 e/wave)
    {
        int e = blk * 4 + wv;
        u32 cw = colcnt[e];
        int cnt = cw < CAPC ? (int)cw : CAPC;
        const u32* ce = colentry + (size_t)e * CAPC;
        float acc0 = 0.f, acc1 = 0.f;
        int i = 0;
        for (; i + 8 <= cnt; i += 8) {
            uint4 a = *((const uint4*)(ce + i));
            uint4 b = *((const uint4*)(ce + i + 4));
            float p0 = P[(a.x & (N_V - 1)) * H0_ + lane];
            float p1 = P[(a.y & (N_V - 1)) * H0_ + lane];
            float p2 = P[(a.z & (N_V - 1)) * H0_ + lane];
            float p3 = P[(a.w & (N_V - 1)) * H0_ + lane];
            float p4 = P[(b.x & (N_V - 1)) * H0_ + lane];
            float p5 = P[(b.y & (N_V - 1)) * H0_ + lane];
            float p6 = P[(b.z & (N_V - 1)) * H0_ + lane];
            float p7 = P[(b.w & (N_V - 1)) * H0_ + lane];
            acc0 += (p0 + p1) + (p2 + p3);
            acc1 += (p4 + p5) + (p6 + p7);
        }
        for (; i < cnt; ++i)
            acc0 += P[(ce[i] & (N_V - 1)) * H0_ + lane];
        Mp[(size_t)e * H0_ + lane] = W[e] * De[e] * (acc0 + acc1);
    }
    grid_sync(bar);   // B: Mp ready

    // ================= stage 3: X1 = leaky(Dv * sum_rownz Mp); BN partials (2 n/wave)
    {
        float (*ssum)[H0_] = (float(*)[H0_])shmem;                // 4x64
        float (*ssq)[H0_]  = (float(*)[H0_])(shmem + 1024);       // 4x64
        float lsum = 0.f, lsq = 0.f;
#pragma unroll 1
        for (int rr = 0; rr < 2; ++rr) {
            int n = blk * 8 + wv * 2 + rr;
            const u32* lrow = nzlist + (size_t)n * CAP;
            u32 cw = nzcnt[n];
            int cnt = cw < CAP ? (int)cw : CAP;
            float acc0 = 0.f, acc1 = 0.f;
            int i = 0;
            for (; i + 8 <= cnt; i += 8) {
                uint4 a = *((const uint4*)(lrow + i));
                uint4 b = *((const uint4*)(lrow + i + 4));
                float p0 = Mp[(a.x & (N_E - 1)) * H0_ + lane];
                float p1 = Mp[(a.y & (N_E - 1)) * H0_ + lane];
                float p2 = Mp[(a.z & (N_E - 1)) * H0_ + lane];
                float p3 = Mp[(a.w & (N_E - 1)) * H0_ + lane];
                float p4 = Mp[(b.x & (N_E - 1)) * H0_ + lane];
                float p5 = Mp[(b.y & (N_E - 1)) * H0_ + lane];
                float p6 = Mp[(b.z & (N_E - 1)) * H0_ + lane];
                float p7 = Mp[(b.w & (N_E - 1)) * H0_ + lane];
                acc0 += (p0 + p1) + (p2 + p3);
                acc1 += (p4 + p5) + (p6 + p7);
            }
            for (; i < cnt; ++i)
                acc0 += Mp[(lrow[i] & (N_E - 1)) * H0_ + lane];
            float xb = Dv[n] * (acc0 + acc1);
            float x1 = xb > 0.f ? xb : 0.01f * xb;
            P[(size_t)n * H0_ + lane] = x1;        // X1 aliases P (P dead after stage 2)
            lsum += x1;
            lsq += x1 * x1;
        }
        ssum[wv][lane] = lsum;
        ssq[wv][lane] = lsq;
        __syncthreads();
        if (wv == 0) {
            float a = ssum[0][lane] + ssum[1][lane] + ssum[2][lane] + ssum[3][lane];
            float b = ssq[0][lane] + ssq[1][lane] + ssq[2][lane] + ssq[3][lane];
            float* dst = bnp + (size_t)(blk & 7) * 128;    // 8-way replicated
            atomicAdd(&dst[lane], a);
            atomicAdd(&dst[64 + lane], b);
        }
    }
    grid_sync(bar);   // C: bnp ready (X1 rows are same-wave)

    // ================= stage 4: BN apply + th2 dot -> P2  (2 n/wave)
    {
        float sum = 0.f, sq = 0.f;
#pragma unroll
        for (int p = 0; p < 8; ++p) { sum += bnp[p * 128 + lane]; sq += bnp[p * 128 + 64 + lane]; }
        float mu = sum * (1.f / N_V);
        float var = sq * (1.f / N_V) - mu * mu;
        float inv = rsqrtf(var + BN_EPS);
        float g = gm[lane], b0 = bt[lane], t2 = th2[lane];
#pragma unroll 1
        for (int rr = 0; rr < 2; ++rr) {
            int n = blk * 8 + wv * 2 + rr;
            float x = P[(size_t)n * H0_ + lane];           // own wave's X1
            float xn = (x - mu) * inv * g + b0;
            float t = xn * t2;
#pragma unroll
            for (int off = 32; off > 0; off >>= 1) t += __shfl_xor(t, off);
            if (lane == 0) P2[n] = Dv[n] * t;
        }
    }
    grid_sync(bar);   // D: P2 ready

    // ================= stage 5: M2p[e] = W*De * sum_colnz P2[n]  (1 e/wave)
    {
        int e = blk * 4 + wv;
        u32 cw = colcnt[e];
        int cnt = cw < CAPC ? (int)cw : CAPC;
        const u32* ce = colentry + (size_t)e * CAPC;
        float s = 0.f;
        for (int i = lane; i < cnt; i += 64)
            s += P2[ce[i] & (N_V - 1)];
#pragma unroll
        for (int off = 32; off > 0; off >>= 1) s += __shfl_xor(s, off);
        if (lane == 0) M2p[e] = W[e] * De[e] * s;
    }
    grid_sync(bar);   // E: M2p ready

    // ================= stage 6: out[n] = sigmoid(Dv * sum_rownz M2p)  (2 n/wave)
    {
#pragma unroll 1
        for (int rr = 0; rr < 2; ++rr) {
            int n = blk * 8 + wv * 2 + rr;
            u32 cw = nzcnt[n];
            int cnt = cw < CAP ? (int)cw : CAP;
            const u32* lrow = nzlist + (size_t)n * CAP;
            float s = 0.f;
            for (int i = lane; i < cnt; i += 64)
                s += M2p[lrow[i] & (N_E - 1)];
#pragma unroll
            for (int off = 32; off > 0; off >>= 1) s += __shfl_xor(s, off);
            if (lane == 0) {
                float xb = Dv[n] * s;
                out[n] = 1.f / (1.f + expf(-xb));
            }
        }
    }
}

extern "C" void kernel_launch(void* const* d_in, const int* in_sizes, int n_in,
                              void* d_out, int out_size, void* d_ws, size_t ws_size,
                              hipStream_t stream) {
    const float* X   = (const float*)d_in[0];
    const float* Dv  = (const float*)d_in[1];
    const float* De  = (const float*)d_in[2];
    const float* Hf  = (const float*)d_in[3];
    const float* W   = (const float*)d_in[4];
    const float* th1 = (const float*)d_in[5];
    const float* th2 = (const float*)d_in[6];
    const float* gm  = (const float*)d_in[7];
    const float* bt  = (const float*)d_in[8];

    char* ws = (char*)d_ws;
    u32*   colcnt   = (u32*)  (ws + 0);          // 16384
    float* bnp      = (float*)(ws + 16384);      // 4096
    u32*   bar      = (u32*)  (ws + 20480);      // 4 (+pad)  -> zero [0, 20736)
    u32*   nzcnt    = (u32*)  (ws + 24576);      // 32768   -> 57344
    float* M2p      = (float*)(ws + 57344);      // 16384   -> 73728
    float* P2       = (float*)(ws + 73728);      // 32768   -> 106496
    float* P        = (float*)(ws + 106496);     // 2 MB    -> 2203648  (X1 aliases)
    float* Mp       = (float*)(ws + 2203648);    // 1 MB    -> 3252224
    u32*   nzlist   = (u32*)  (ws + 3252224);    // 3 MB    -> 6397952
    u32*   colentry = (u32*)  (ws + 6397952);    // 2.25 MB -> 8757248

    hipMemsetAsync(ws, 0, 20736, stream);
    k_fused<<<GRID, 256, 0, stream>>>(X, th1, Dv, De, Hf, W, th2, gm, bt,
                                      P, Mp, nzlist, nzcnt, colcnt, colentry,
                                      bnp, P2, M2p, bar, (float*)d_out);
}

// Round 12
// 342.628 us; speedup vs baseline: 3.6285x; 3.6285x over previous
//
#include <hip/hip_runtime.h>
#include <math.h>

#define N_V   8192
#define N_E   4096
#define V_HID 128
#define H0_   64
#define CAP   96      // row nz capacity  (mean 41, sigma 6.4)
#define CAPC  144     // col nz capacity  (mean 82, sigma 9.0)
#define BN_EPS 1e-5f
#define GRID_T 256u   // tail kernel grid: 1 block/CU, trivially co-resident

typedef unsigned int u32;
typedef unsigned long long u64;

// ===== KA: proj (stage0) + H-scan (stage1), independent work, no grid sync
__global__ __launch_bounds__(256) void ka_proj_scan(
    const float* __restrict__ X, const float* __restrict__ th1,
    const float* __restrict__ Dv, const float* __restrict__ Hf,
    float* __restrict__ P,
    u32* __restrict__ nzlist, u32* __restrict__ nzcnt,
    u32* __restrict__ colcnt, u32* __restrict__ colentry)
{
    __shared__ __align__(16) char shmem[36 * 1024];
    int tid = threadIdx.x;
    int lane = tid & 63, wv = tid >> 6;
    int blk = blockIdx.x;

    // ---- stage 0: P[n,h] = Dv[n]*(X@th1)[n,h], 8 rows/block
    {
        float (*Th)[H0_]   = (float(*)[H0_])shmem;               // 32 KB
        float (*Xs)[V_HID] = (float(*)[V_HID])(shmem + 32768);   // 4 KB
        int n0 = blk * 8;
        for (int i = tid; i < 2048; i += 256) {
            float4 f = ((const float4*)th1)[i];
            int b = 4 * i;
            Th[b >> 6][(b & 63) + 0] = f.x;
            Th[b >> 6][(b & 63) + 1] = f.y;
            Th[b >> 6][(b & 63) + 2] = f.z;
            Th[b >> 6][(b & 63) + 3] = f.w;
        }
        {
            float4 f = ((const float4*)(X + (size_t)n0 * V_HID))[tid];
            int b = 4 * tid;
            Xs[b >> 7][(b & 127) + 0] = f.x;
            Xs[b >> 7][(b & 127) + 1] = f.y;
            Xs[b >> 7][(b & 127) + 2] = f.z;
            Xs[b >> 7][(b & 127) + 3] = f.w;
        }
        __syncthreads();
        int r0 = wv * 2;
        float a0 = 0.f, a1 = 0.f;
        for (int k = 0; k < V_HID; ++k) {
            float t = Th[k][lane];
            a0 += t * Xs[r0 + 0][k];
            a1 += t * Xs[r0 + 1][k];
        }
        P[(size_t)(n0 + r0 + 0) * H0_ + lane] = Dv[n0 + r0 + 0] * a0;
        P[(size_t)(n0 + r0 + 1) * H0_ + lane] = Dv[n0 + r0 + 1] * a1;
        __syncthreads();     // shmem dead before scan reuses it
    }

    // ---- stage 1: scan 8 H rows/block (2/wave). Whole 16 KB row in flight
    // (16 coalesced uint4/lane), decoded in 4 chunks of 1024 elems.
    // Load map: q[m] = hrow4[m*64+lane] -> q[4cc+k] covers float index
    //   1024*cc + 256*k + 4*lane + comp. Bit j of mask (k=j>>2, comp=j&3)
    //   => e = 1024*cc + 256*(j>>2) + 4*lane + (j&3).   [R11 bug: used lane*16+j]
    {
        u32 (*rowbuf)[CAP] = (u32(*)[CAP])shmem;
#pragma unroll 1
        for (int rr = 0; rr < 2; ++rr) {
            int n = blk * 8 + wv * 2 + rr;
            const uint4* hrow4 = (const uint4*)(Hf + (size_t)n * N_E);
            uint4 q[16];
#pragma unroll
            for (int m = 0; m < 16; ++m)            // full row in flight
                q[m] = hrow4[m * 64 + lane];
            u32 cnt = 0;
#pragma unroll
            for (int cc = 0; cc < 4; ++cc) {
                uint4 q0 = q[4 * cc + 0], q1 = q[4 * cc + 1];
                uint4 q2 = q[4 * cc + 2], q3 = q[4 * cc + 3];
                u32 m = 0;
                m |= (q0.x != 0u) ? 1u << 0  : 0u;  m |= (q0.y != 0u) ? 1u << 1  : 0u;
                m |= (q0.z != 0u) ? 1u << 2  : 0u;  m |= (q0.w != 0u) ? 1u << 3  : 0u;
                m |= (q1.x != 0u) ? 1u << 4  : 0u;  m |= (q1.y != 0u) ? 1u << 5  : 0u;
                m |= (q1.z != 0u) ? 1u << 6  : 0u;  m |= (q1.w != 0u) ? 1u << 7  : 0u;
                m |= (q2.x != 0u) ? 1u << 8  : 0u;  m |= (q2.y != 0u) ? 1u << 9  : 0u;
                m |= (q2.z != 0u) ? 1u << 10 : 0u;  m |= (q2.w != 0u) ? 1u << 11 : 0u;
                m |= (q3.x != 0u) ? 1u << 12 : 0u;  m |= (q3.y != 0u) ? 1u << 13 : 0u;
                m |= (q3.z != 0u) ? 1u << 14 : 0u;  m |= (q3.w != 0u) ? 1u << 15 : 0u;
                u32 cl = (u32)__popc(m);
                u32 pre = cl;                        // inclusive prefix sum
#pragma unroll
                for (int off = 1; off <= 32; off <<= 1) {
                    u32 t = __shfl_up(pre, off);
                    if (lane >= off) pre += t;
                }
                u32 slot = cnt + pre - cl;           // exclusive + running base
                u32 chunk_total = __shfl(pre, 63);
                u32 mm = m;
                while (mm) {
                    int j = __ffs(mm) - 1;
                    mm &= mm - 1;
                    u32 e = (u32)(cc * 1024 + ((j >> 2) << 8) + (lane << 2) + (j & 3));
                    if (slot < CAP) rowbuf[wv][slot] = e;
                    slot++;
                }
                cnt += chunk_total;
            }
            if (cnt > CAP) cnt = CAP;
            if (lane == 0) nzcnt[n] = cnt;
            for (u32 i = lane; i < cnt; i += 64) {
                u32 e = rowbuf[wv][i];
                nzlist[(size_t)n * CAP + i] = e;
                u32 cs = atomicAdd(&colcnt[e], 1u);
                if (cs < CAPC) colentry[(size_t)e * CAPC + cs] = (u32)n;
            }
        }
    }
}

// ===== KB: Mp[e,:] = W*De * sum_colnz P[n,:]
__global__ __launch_bounds__(256) void kb_gather(const u32* __restrict__ colcnt, const u32* __restrict__ colentry,
                                                 const float* __restrict__ P, const float* __restrict__ W,
                                                 const float* __restrict__ De, float* __restrict__ Mp) {
    int lane = threadIdx.x & 63;
    int e = blockIdx.x * 4 + (threadIdx.x >> 6);
    u32 cw = colcnt[e];
    int cnt = cw < CAPC ? (int)cw : CAPC;
    const u32* ce = colentry + (size_t)e * CAPC;
    float acc0 = 0.f, acc1 = 0.f;
    int i = 0;
    for (; i + 8 <= cnt; i += 8) {
        uint4 a = *((const uint4*)(ce + i));
        uint4 b = *((const uint4*)(ce + i + 4));
        float p0 = P[(a.x & (N_V - 1)) * H0_ + lane];
        float p1 = P[(a.y & (N_V - 1)) * H0_ + lane];
        float p2 = P[(a.z & (N_V - 1)) * H0_ + lane];
        float p3 = P[(a.w & (N_V - 1)) * H0_ + lane];
        float p4 = P[(b.x & (N_V - 1)) * H0_ + lane];
        float p5 = P[(b.y & (N_V - 1)) * H0_ + lane];
        float p6 = P[(b.z & (N_V - 1)) * H0_ + lane];
        float p7 = P[(b.w & (N_V - 1)) * H0_ + lane];
        acc0 += (p0 + p1) + (p2 + p3);
        acc1 += (p4 + p5) + (p6 + p7);
    }
    for (; i < cnt; ++i)
        acc0 += P[(ce[i] & (N_V - 1)) * H0_ + lane];
    Mp[(size_t)e * H0_ + lane] = W[e] * De[e] * (acc0 + acc1);
}

// ===== KC: X1 = leaky(Dv*sum_rownz Mp); BN partial sums (X1 aliases P)
__global__ __launch_bounds__(256) void kc_layer1(const u32* __restrict__ nzlist, const u32* __restrict__ nzcnt,
                                                 const float* __restrict__ Mp, const float* __restrict__ Dv,
                                                 float* __restrict__ X1, float* __restrict__ bnp) {
    int lane = threadIdx.x & 63;
    int wv = threadIdx.x >> 6;
    int n = blockIdx.x * 4 + wv;
    const u32* lrow = nzlist + (size_t)n * CAP;
    u32 cw = nzcnt[n];
    int cnt = cw < CAP ? (int)cw : CAP;
    float acc0 = 0.f, acc1 = 0.f;
    int i = 0;
    for (; i + 8 <= cnt; i += 8) {
        uint4 a = *((const uint4*)(lrow + i));
        uint4 b = *((const uint4*)(lrow + i + 4));
        float p0 = Mp[(a.x & (N_E - 1)) * H0_ + lane];
        float p1 = Mp[(a.y & (N_E - 1)) * H0_ + lane];
        float p2 = Mp[(a.z & (N_E - 1)) * H0_ + lane];
        float p3 = Mp[(a.w & (N_E - 1)) * H0_ + lane];
        float p4 = Mp[(b.x & (N_E - 1)) * H0_ + lane];
        float p5 = Mp[(b.y & (N_E - 1)) * H0_ + lane];
        float p6 = Mp[(b.z & (N_E - 1)) * H0_ + lane];
        float p7 = Mp[(b.w & (N_E - 1)) * H0_ + lane];
        acc0 += (p0 + p1) + (p2 + p3);
        acc1 += (p4 + p5) + (p6 + p7);
    }
    for (; i < cnt; ++i)
        acc0 += Mp[(lrow[i] & (N_E - 1)) * H0_ + lane];
    float xb = Dv[n] * (acc0 + acc1);
    float x1 = xb > 0.f ? xb : 0.01f * xb;
    X1[(size_t)n * H0_ + lane] = x1;
    __shared__ float ssum[4][H0_], ssq[4][H0_];
    ssum[wv][lane] = x1;
    ssq[wv][lane] = x1 * x1;
    __syncthreads();
    if (wv == 0) {
        float a = ssum[0][lane] + ssum[1][lane] + ssum[2][lane] + ssum[3][lane];
        float b = ssq[0][lane] + ssq[1][lane] + ssq[2][lane] + ssq[3][lane];
        float* dst = bnp + (size_t)(blockIdx.x & 7) * 128;
        atomicAdd(&dst[lane], a);
        atomicAdd(&dst[64 + lane], b);
    }
}

// ===== KD: tail (BN+proj2 -> edge2 -> out), grid=256, 2 internal barriers
__device__ __forceinline__ void gsync256(u32* leaf, u32* root, int blk) {
    __threadfence();
    __syncthreads();
    if (threadIdx.x == 0) {
        u32* myleaf = leaf + (blk & 7) * 32;             // 128 B stride
        u32 t = __hip_atomic_fetch_add(myleaf, 1u, __ATOMIC_RELEASE, __HIP_MEMORY_SCOPE_AGENT);
        u32 gen = t >> 5;                                // 32 blocks per leaf
        if ((t & 31u) == 31u)
            __hip_atomic_fetch_add(root, 1u, __ATOMIC_RELEASE, __HIP_MEMORY_SCOPE_AGENT);
        u32 target = (gen + 1u) * 8u;
        while (__hip_atomic_load(root, __ATOMIC_ACQUIRE, __HIP_MEMORY_SCOPE_AGENT) < target)
            __builtin_amdgcn_s_sleep(4);
    }
    __syncthreads();
    __threadfence();
}

__global__ __launch_bounds__(256) void kd_tail(
    const float* __restrict__ X1, const float* __restrict__ bnp,
    const float* __restrict__ gm, const float* __restrict__ bt,
    const float* __restrict__ th2, const float* __restrict__ Dv,
    const float* __restrict__ W, const float* __restrict__ De,
    const u32* __restrict__ nzlist, const u32* __restrict__ nzcnt,
    const u32* __restrict__ colcnt, const u32* __restrict__ colentry,
    float* __restrict__ P2, float* __restrict__ M2p,
    u32* leaf, u32* root, float* __restrict__ out)
{
    int tid = threadIdx.x;
    int lane = tid & 63, wv = tid >> 6;
    int blk = blockIdx.x;

    // stage A: BN apply + th2 dot -> P2   (8 rows/wave)
    {
        float sum = 0.f, sq = 0.f;
#pragma unroll
        for (int p = 0; p < 8; ++p) { sum += bnp[p * 128 + lane]; sq += bnp[p * 128 + 64 + lane]; }
        float mu = sum * (1.f / N_V);
        float var = sq * (1.f / N_V) - mu * mu;
        float inv = rsqrtf(var + BN_EPS);
        float g = gm[lane], b0 = bt[lane], t2 = th2[lane];
#pragma unroll 1
        for (int rr = 0; rr < 8; ++rr) {
            int n = blk * 32 + wv * 8 + rr;
            float x = X1[(size_t)n * H0_ + lane];
            float xn = (x - mu) * inv * g + b0;
            float t = xn * t2;
#pragma unroll
            for (int off = 32; off > 0; off >>= 1) t += __shfl_xor(t, off);
            if (lane == 0) P2[n] = Dv[n] * t;
        }
    }
    gsync256(leaf, root, blk);

    // stage B: M2p[e] = W*De * sum_colnz P2   (4 e/wave)
    {
#pragma unroll 1
        for (int rr = 0; rr < 4; ++rr) {
            int e = blk * 16 + wv * 4 + rr;
            u32 cw = colcnt[e];
            int cnt = cw < CAPC ? (int)cw : CAPC;
            const u32* ce = colentry + (size_t)e * CAPC;
            float s = 0.f;
            for (int i = lane; i < cnt; i += 64)
                s += P2[ce[i] & (N_V - 1)];
#pragma unroll
            for (int off = 32; off > 0; off >>= 1) s += __shfl_xor(s, off);
            if (lane == 0) M2p[e] = W[e] * De[e] * s;
        }
    }
    gsync256(leaf, root, blk);

    // stage C: out[n] = sigmoid(Dv * sum_rownz M2p)   (8 n/wave)
    {
#pragma unroll 1
        for (int rr = 0; rr < 8; ++rr) {
            int n = blk * 32 + wv * 8 + rr;
            u32 cw = nzcnt[n];
            int cnt = cw < CAP ? (int)cw : CAP;
            const u32* lrow = nzlist + (size_t)n * CAP;
            float s = 0.f;
            for (int i = lane; i < cnt; i += 64)
                s += M2p[lrow[i] & (N_E - 1)];
#pragma unroll
            for (int off = 32; off > 0; off >>= 1) s += __shfl_xor(s, off);
            if (lane == 0) {
                float xb = Dv[n] * s;
                out[n] = 1.f / (1.f + expf(-xb));
            }
        }
    }
}

extern "C" void kernel_launch(void* const* d_in, const int* in_sizes, int n_in,
                              void* d_out, int out_size, void* d_ws, size_t ws_size,
                              hipStream_t stream) {
    const float* X   = (const float*)d_in[0];
    const float* Dv  = (const float*)d_in[1];
    const float* De  = (const float*)d_in[2];
    const float* Hf  = (const float*)d_in[3];
    const float* W   = (const float*)d_in[4];
    const float* th1 = (const float*)d_in[5];
    const float* th2 = (const float*)d_in[6];
    const float* gm  = (const float*)d_in[7];
    const float* bt  = (const float*)d_in[8];

    char* ws = (char*)d_ws;
    u32*   colcnt   = (u32*)  (ws + 0);          // 16384
    float* bnp      = (float*)(ws + 16384);      // 4096  -> 20480
    u32*   leaf     = (u32*)  (ws + 20480);      // 8*32*4 = 1024 -> 21504
    u32*   root     = (u32*)  (ws + 21504);      // 4  (zero region ends 21632)
    u32*   nzcnt    = (u32*)  (ws + 24576);      // 32768   -> 57344
    float* M2p      = (float*)(ws + 57344);      // 16384   -> 73728
    float* P2       = (float*)(ws + 73728);      // 32768   -> 106496
    float* P        = (float*)(ws + 106496);     // 2 MB    -> 2203648  (X1 aliases)
    float* Mp       = (float*)(ws + 2203648);    // 1 MB    -> 3252224
    u32*   nzlist   = (u32*)  (ws + 3252224);    // 3 MB    -> 6397952
    u32*   colentry = (u32*)  (ws + 6397952);    // 2.25 MB -> 8757248

    hipMemsetAsync(ws, 0, 21632, stream);
    ka_proj_scan<<<N_V / 8, 256, 0, stream>>>(X, th1, Dv, Hf, P, nzlist, nzcnt, colcnt, colentry);
    kb_gather<<<N_E / 4, 256, 0, stream>>>(colcnt, colentry, P, W, De, Mp);
    kc_layer1<<<N_V / 4, 256, 0, stream>>>(nzlist, nzcnt, Mp, Dv, P, bnp);
    kd_tail<<<GRID_T, 256, 0, stream>>>(P, bnp, gm, bt, th2, Dv, W, De,
                                        nzlist, nzcnt, colcnt, colentry,
                                        P2, M2p, leaf, root, (float*)d_out);
}

// Round 13
// 303.205 us; speedup vs baseline: 4.1003x; 1.1300x over previous
//
#include <hip/hip_runtime.h>
#include <math.h>

#define N_V   8192
#define N_E   4096
#define V_HID 128
#define H0_   64
#define CAP   96      // row nz capacity  (mean 41, sigma 6.4)
#define CAPC  144     // col nz capacity  (mean 82, sigma 9.0)
#define BN_EPS 1e-5f
#define GRID_T 256u   // tail kernel grid: 1 block/CU, trivially co-resident

typedef unsigned int u32;
typedef unsigned long long u64;

// ===== KA: proj (stage0) + H-scan (stage1), independent work, no grid sync
__global__ __launch_bounds__(256) void ka_proj_scan(
    const float* __restrict__ X, const float* __restrict__ th1,
    const float* __restrict__ Dv, const float* __restrict__ Hf,
    float* __restrict__ P,
    u32* __restrict__ nzlist, u32* __restrict__ nzcnt,
    u32* __restrict__ colcnt, u32* __restrict__ colentry)
{
    __shared__ __align__(16) char shmem[36 * 1024];
    int tid = threadIdx.x;
    int lane = tid & 63, wv = tid >> 6;
    int blk = blockIdx.x;

    // ---- stage 0: P[n,h] = Dv[n]*(X@th1)[n,h], 8 rows/block
    {
        float (*Th)[H0_]   = (float(*)[H0_])shmem;               // 32 KB
        float (*Xs)[V_HID] = (float(*)[V_HID])(shmem + 32768);   // 4 KB
        int n0 = blk * 8;
        for (int i = tid; i < 2048; i += 256) {
            float4 f = ((const float4*)th1)[i];
            int b = 4 * i;
            Th[b >> 6][(b & 63) + 0] = f.x;
            Th[b >> 6][(b & 63) + 1] = f.y;
            Th[b >> 6][(b & 63) + 2] = f.z;
            Th[b >> 6][(b & 63) + 3] = f.w;
        }
        {
            float4 f = ((const float4*)(X + (size_t)n0 * V_HID))[tid];
            int b = 4 * tid;
            Xs[b >> 7][(b & 127) + 0] = f.x;
            Xs[b >> 7][(b & 127) + 1] = f.y;
            Xs[b >> 7][(b & 127) + 2] = f.z;
            Xs[b >> 7][(b & 127) + 3] = f.w;
        }
        __syncthreads();
        int r0 = wv * 2;
        float a0 = 0.f, a1 = 0.f;
        for (int k = 0; k < V_HID; ++k) {
            float t = Th[k][lane];
            a0 += t * Xs[r0 + 0][k];
            a1 += t * Xs[r0 + 1][k];
        }
        P[(size_t)(n0 + r0 + 0) * H0_ + lane] = Dv[n0 + r0 + 0] * a0;
        P[(size_t)(n0 + r0 + 1) * H0_ + lane] = Dv[n0 + r0 + 1] * a1;
        __syncthreads();     // shmem dead before scan reuses it
    }

    // ---- stage 1: scan 8 H rows/block (2/wave). Whole 16 KB row in flight
    // (16 coalesced uint4/lane), decoded in 4 chunks of 1024 elems.
    // Load map: q[4cc+k] covers float index 1024*cc + 256*k + 4*lane + comp
    //   => bit j (k=j>>2, comp=j&3): e = 1024*cc + 256*(j>>2) + 4*lane + (j&3)
    {
        u32 (*rowbuf)[CAP] = (u32(*)[CAP])shmem;
#pragma unroll 1
        for (int rr = 0; rr < 2; ++rr) {
            int n = blk * 8 + wv * 2 + rr;
            const uint4* hrow4 = (const uint4*)(Hf + (size_t)n * N_E);
            uint4 q[16];
#pragma unroll
            for (int m = 0; m < 16; ++m)            // full row in flight
                q[m] = hrow4[m * 64 + lane];
            u32 cnt = 0;
#pragma unroll
            for (int cc = 0; cc < 4; ++cc) {
                uint4 q0 = q[4 * cc + 0], q1 = q[4 * cc + 1];
                uint4 q2 = q[4 * cc + 2], q3 = q[4 * cc + 3];
                u32 m = 0;
                m |= (q0.x != 0u) ? 1u << 0  : 0u;  m |= (q0.y != 0u) ? 1u << 1  : 0u;
                m |= (q0.z != 0u) ? 1u << 2  : 0u;  m |= (q0.w != 0u) ? 1u << 3  : 0u;
                m |= (q1.x != 0u) ? 1u << 4  : 0u;  m |= (q1.y != 0u) ? 1u << 5  : 0u;
                m |= (q1.z != 0u) ? 1u << 6  : 0u;  m |= (q1.w != 0u) ? 1u << 7  : 0u;
                m |= (q2.x != 0u) ? 1u << 8  : 0u;  m |= (q2.y != 0u) ? 1u << 9  : 0u;
                m |= (q2.z != 0u) ? 1u << 10 : 0u;  m |= (q2.w != 0u) ? 1u << 11 : 0u;
                m |= (q3.x != 0u) ? 1u << 12 : 0u;  m |= (q3.y != 0u) ? 1u << 13 : 0u;
                m |= (q3.z != 0u) ? 1u << 14 : 0u;  m |= (q3.w != 0u) ? 1u << 15 : 0u;
                u32 cl = (u32)__popc(m);
                u32 pre = cl;                        // inclusive prefix sum
#pragma unroll
                for (int off = 1; off <= 32; off <<= 1) {
                    u32 t = __shfl_up(pre, off);
                    if (lane >= off) pre += t;
                }
                u32 slot = cnt + pre - cl;           // exclusive + running base
                u32 chunk_total = __shfl(pre, 63);
                u32 mm = m;
                while (mm) {
                    int j = __ffs(mm) - 1;
                    mm &= mm - 1;
                    u32 e = (u32)(cc * 1024 + ((j >> 2) << 8) + (lane << 2) + (j & 3));
                    if (slot < CAP) rowbuf[wv][slot] = e;
                    slot++;
                }
                cnt += chunk_total;
            }
            if (cnt > CAP) cnt = CAP;
            if (lane == 0) nzcnt[n] = cnt;
            for (u32 i = lane; i < cnt; i += 64) {
                u32 e = rowbuf[wv][i];
                nzlist[(size_t)n * CAP + i] = e;
                u32 cs = atomicAdd(&colcnt[e], 1u);
                if (cs < CAPC) colentry[(size_t)e * CAPC + cs] = (u32)n;
            }
        }
    }
}

// ===== KB: Mp[e,:] = W*De * sum_colnz P[n,:]
__global__ __launch_bounds__(256) void kb_gather(const u32* __restrict__ colcnt, const u32* __restrict__ colentry,
                                                 const float* __restrict__ P, const float* __restrict__ W,
                                                 const float* __restrict__ De, float* __restrict__ Mp) {
    int lane = threadIdx.x & 63;
    int e = blockIdx.x * 4 + (threadIdx.x >> 6);
    u32 cw = colcnt[e];
    int cnt = cw < CAPC ? (int)cw : CAPC;
    const u32* ce = colentry + (size_t)e * CAPC;
    float acc0 = 0.f, acc1 = 0.f;
    int i = 0;
    for (; i + 8 <= cnt; i += 8) {
        uint4 a = *((const uint4*)(ce + i));
        uint4 b = *((const uint4*)(ce + i + 4));
        float p0 = P[(a.x & (N_V - 1)) * H0_ + lane];
        float p1 = P[(a.y & (N_V - 1)) * H0_ + lane];
        float p2 = P[(a.z & (N_V - 1)) * H0_ + lane];
        float p3 = P[(a.w & (N_V - 1)) * H0_ + lane];
        float p4 = P[(b.x & (N_V - 1)) * H0_ + lane];
        float p5 = P[(b.y & (N_V - 1)) * H0_ + lane];
        float p6 = P[(b.z & (N_V - 1)) * H0_ + lane];
        float p7 = P[(b.w & (N_V - 1)) * H0_ + lane];
        acc0 += (p0 + p1) + (p2 + p3);
        acc1 += (p4 + p5) + (p6 + p7);
    }
    for (; i < cnt; ++i)
        acc0 += P[(ce[i] & (N_V - 1)) * H0_ + lane];
    Mp[(size_t)e * H0_ + lane] = W[e] * De[e] * (acc0 + acc1);
}

// ===== KC: X1 = leaky(Dv*sum_rownz Mp); BN partial sums (X1 aliases P)
__global__ __launch_bounds__(256) void kc_layer1(const u32* __restrict__ nzlist, const u32* __restrict__ nzcnt,
                                                 const float* __restrict__ Mp, const float* __restrict__ Dv,
                                                 float* __restrict__ X1, float* __restrict__ bnp) {
    int lane = threadIdx.x & 63;
    int wv = threadIdx.x >> 6;
    int n = blockIdx.x * 4 + wv;
    const u32* lrow = nzlist + (size_t)n * CAP;
    u32 cw = nzcnt[n];
    int cnt = cw < CAP ? (int)cw : CAP;
    float acc0 = 0.f, acc1 = 0.f;
    int i = 0;
    for (; i + 8 <= cnt; i += 8) {
        uint4 a = *((const uint4*)(lrow + i));
        uint4 b = *((const uint4*)(lrow + i + 4));
        float p0 = Mp[(a.x & (N_E - 1)) * H0_ + lane];
        float p1 = Mp[(a.y & (N_E - 1)) * H0_ + lane];
        float p2 = Mp[(a.z & (N_E - 1)) * H0_ + lane];
        float p3 = Mp[(a.w & (N_E - 1)) * H0_ + lane];
        float p4 = Mp[(b.x & (N_E - 1)) * H0_ + lane];
        float p5 = Mp[(b.y & (N_E - 1)) * H0_ + lane];
        float p6 = Mp[(b.z & (N_E - 1)) * H0_ + lane];
        float p7 = Mp[(b.w & (N_E - 1)) * H0_ + lane];
        acc0 += (p0 + p1) + (p2 + p3);
        acc1 += (p4 + p5) + (p6 + p7);
    }
    for (; i < cnt; ++i)
        acc0 += Mp[(lrow[i] & (N_E - 1)) * H0_ + lane];
    float xb = Dv[n] * (acc0 + acc1);
    float x1 = xb > 0.f ? xb : 0.01f * xb;
    X1[(size_t)n * H0_ + lane] = x1;
    __shared__ float ssum[4][H0_], ssq[4][H0_];
    ssum[wv][lane] = x1;
    ssq[wv][lane] = x1 * x1;
    __syncthreads();
    if (wv == 0) {
        float a = ssum[0][lane] + ssum[1][lane] + ssum[2][lane] + ssum[3][lane];
        float b = ssq[0][lane] + ssq[1][lane] + ssq[2][lane] + ssq[3][lane];
        float* dst = bnp + (size_t)(blockIdx.x & 7) * 128;
        atomicAdd(&dst[lane], a);
        atomicAdd(&dst[64 + lane], b);
    }
}

// ===== KD: tail (BN+proj2 -> edge2 -> out), grid=256, 2 internal barriers
// Spin uses RELAXED atomic loads (no per-poll cache invalidate!) + ONE
// acquire fence after exit — the ROCm cooperative-groups pattern.
__device__ __forceinline__ void gsync256(u32* leaf, u32* root, int blk) {
    __threadfence();                                  // release my writes
    __syncthreads();
    if (threadIdx.x == 0) {
        u32* myleaf = leaf + (blk & 7) * 32;          // 128 B stride
        u32 t = __hip_atomic_fetch_add(myleaf, 1u, __ATOMIC_RELEASE, __HIP_MEMORY_SCOPE_AGENT);
        u32 gen = t >> 5;                             // 32 blocks per leaf
        if ((t & 31u) == 31u)
            __hip_atomic_fetch_add(root, 1u, __ATOMIC_RELEASE, __HIP_MEMORY_SCOPE_AGENT);
        u32 target = (gen + 1u) * 8u;
        while (__hip_atomic_load(root, __ATOMIC_RELAXED, __HIP_MEMORY_SCOPE_AGENT) < target)
            __builtin_amdgcn_s_sleep(1);
        __builtin_amdgcn_fence(__ATOMIC_ACQUIRE, "agent");   // one acquire, after exit
    }
    __syncthreads();
}

__global__ __launch_bounds__(256) void kd_tail(
    const float* __restrict__ X1, const float* __restrict__ bnp,
    const float* __restrict__ gm, const float* __restrict__ bt,
    const float* __restrict__ th2, const float* __restrict__ Dv,
    const float* __restrict__ W, const float* __restrict__ De,
    const u32* __restrict__ nzlist, const u32* __restrict__ nzcnt,
    const u32* __restrict__ colcnt, const u32* __restrict__ colentry,
    float* __restrict__ P2, float* __restrict__ M2p,
    u32* leaf, u32* root, float* __restrict__ out)
{
    int tid = threadIdx.x;
    int lane = tid & 63, wv = tid >> 6;
    int blk = blockIdx.x;

    // stage A: BN apply + th2 dot -> P2   (8 rows/wave)
    {
        float sum = 0.f, sq = 0.f;
#pragma unroll
        for (int p = 0; p < 8; ++p) { sum += bnp[p * 128 + lane]; sq += bnp[p * 128 + 64 + lane]; }
        float mu = sum * (1.f / N_V);
        float var = sq * (1.f / N_V) - mu * mu;
        float inv = rsqrtf(var + BN_EPS);
        float g = gm[lane], b0 = bt[lane], t2 = th2[lane];
#pragma unroll 1
        for (int rr = 0; rr < 8; ++rr) {
            int n = blk * 32 + wv * 8 + rr;
            float x = X1[(size_t)n * H0_ + lane];
            float xn = (x - mu) * inv * g + b0;
            float t = xn * t2;
#pragma unroll
            for (int off = 32; off > 0; off >>= 1) t += __shfl_xor(t, off);
            if (lane == 0) P2[n] = Dv[n] * t;
        }
    }
    gsync256(leaf, root, blk);

    // stage B: M2p[e] = W*De * sum_colnz P2   (4 e/wave)
    {
#pragma unroll 1
        for (int rr = 0; rr < 4; ++rr) {
            int e = blk * 16 + wv * 4 + rr;
            u32 cw = colcnt[e];
            int cnt = cw < CAPC ? (int)cw : CAPC;
            const u32* ce = colentry + (size_t)e * CAPC;
            float s = 0.f;
            for (int i = lane; i < cnt; i += 64)
                s += P2[ce[i] & (N_V - 1)];
#pragma unroll
            for (int off = 32; off > 0; off >>= 1) s += __shfl_xor(s, off);
            if (lane == 0) M2p[e] = W[e] * De[e] * s;
        }
    }
    gsync256(leaf, root, blk);

    // stage C: out[n] = sigmoid(Dv * sum_rownz M2p)   (8 n/wave)
    {
#pragma unroll 1
        for (int rr = 0; rr < 8; ++rr) {
            int n = blk * 32 + wv * 8 + rr;
            u32 cw = nzcnt[n];
            int cnt = cw < CAP ? (int)cw : CAP;
            const u32* lrow = nzlist + (size_t)n * CAP;
            float s = 0.f;
            for (int i = lane; i < cnt; i += 64)
                s += M2p[lrow[i] & (N_E - 1)];
#pragma unroll
            for (int off = 32; off > 0; off >>= 1) s += __shfl_xor(s, off);
            if (lane == 0) {
                float xb = Dv[n] * s;
                out[n] = 1.f / (1.f + expf(-xb));
            }
        }
    }
}

extern "C" void kernel_launch(void* const* d_in, const int* in_sizes, int n_in,
                              void* d_out, int out_size, void* d_ws, size_t ws_size,
                              hipStream_t stream) {
    const float* X   = (const float*)d_in[0];
    const float* Dv  = (const float*)d_in[1];
    const float* De  = (const float*)d_in[2];
    const float* Hf  = (const float*)d_in[3];
    const float* W   = (const float*)d_in[4];
    const float* th1 = (const float*)d_in[5];
    const float* th2 = (const float*)d_in[6];
    const float* gm  = (const float*)d_in[7];
    const float* bt  = (const float*)d_in[8];

    char* ws = (char*)d_ws;
    u32*   colcnt   = (u32*)  (ws + 0);          // 16384
    float* bnp      = (float*)(ws + 16384);      // 4096  -> 20480
    u32*   leaf     = (u32*)  (ws + 20480);      // 8*32*4 = 1024 -> 21504
    u32*   root     = (u32*)  (ws + 21504);      // 4  (zero region ends 21632)
    u32*   nzcnt    = (u32*)  (ws + 24576);      // 32768   -> 57344
    float* M2p      = (float*)(ws + 57344);      // 16384   -> 73728
    float* P2       = (float*)(ws + 73728);      // 32768   -> 106496
    float* P        = (float*)(ws + 106496);     // 2 MB    -> 2203648  (X1 aliases)
    float* Mp       = (float*)(ws + 2203648);    // 1 MB    -> 3252224
    u32*   nzlist   = (u32*)  (ws + 3252224);    // 3 MB    -> 6397952
    u32*   colentry = (u32*)  (ws + 6397952);    // 2.25 MB -> 8757248

    hipMemsetAsync(ws, 0, 21632, stream);
    ka_proj_scan<<<N_V / 8, 256, 0, stream>>>(X, th1, Dv, Hf, P, nzlist, nzcnt, colcnt, colentry);
    kb_gather<<<N_E / 4, 256, 0, stream>>>(colcnt, colentry, P, W, De, Mp);
    kc_layer1<<<N_V / 4, 256, 0, stream>>>(nzlist, nzcnt, Mp, Dv, P, bnp);
    kd_tail<<<GRID_T, 256, 0, stream>>>(P, bnp, gm, bt, th2, Dv, W, De,
                                        nzlist, nzcnt, colcnt, colentry,
                                        P2, M2p, leaf, root, (float*)d_out);
}